// Round 6
// baseline (256.213 us; speedup 1.0000x reference)
//
#include <hip/hip_runtime.h>
#include <stdint.h>

// Problem constants
#define BB 4
#define TT 2048
#define CC 1024
#define HH 16
#define DD 64
#define MM (BB * TT)   // 8192 rows for QKV projection

typedef unsigned short u16;
typedef unsigned int   u32;
typedef __attribute__((ext_vector_type(8))) short short8;   // 8 bf16 (4 VGPRs)
typedef _Float16 half8  __attribute__((ext_vector_type(8)));
typedef __fp16   fp16x2 __attribute__((ext_vector_type(2)));
typedef __attribute__((ext_vector_type(4))) float f32x4;    // MFMA C/D
typedef __attribute__((ext_vector_type(4))) unsigned short u16x4;
typedef __attribute__((ext_vector_type(4))) unsigned int u32x4;

#if __has_builtin(__builtin_amdgcn_exp2f)
#define EXP2(x) __builtin_amdgcn_exp2f(x)
#else
#define EXP2(x) __expf(0.69314718055994531f * (x))
#endif

__device__ inline u16 f2bf(float f) {
    union { float f; unsigned u; } v; v.f = f;
    unsigned r = 0x7fffu + ((v.u >> 16) & 1u);   // RNE
    return (u16)((v.u + r) >> 16);
}
__device__ inline u16 f2h(float f) {
    union { _Float16 h; u16 u; } c; c.h = (_Float16)f; return c.u;
}
__device__ inline u32 pkh(float a, float b) {   // pack 2 f32 -> f16x2 (v_cvt_pkrtz)
    union { fp16x2 h; u32 u; } c;
    c.h = __builtin_amdgcn_cvt_pkrtz(a, b);
    return c.u;
}
__device__ inline void load_lds16(const u16* g, u16* l) {
    __builtin_amdgcn_global_load_lds((const __attribute__((address_space(1))) void*)g,
                                     (__attribute__((address_space(3))) void*)l, 16, 0, 0);
}

// ---------------------------------------------------------------- convert (fused)
#define NX (MM * CC / 4)   // x float4 count
#define NW (CC * CC / 4)   // one W float4 count
__global__ void cvt_all(const float* __restrict__ x,  const float* __restrict__ Wq,
                        const float* __restrict__ Wk, const float* __restrict__ Wv,
                        u16* __restrict__ xb, u16* __restrict__ Wb) {
    int i = blockIdx.x * blockDim.x + threadIdx.x;
    const float* src; u16* dst; int j;
    if (i < NX)               { src = x;  dst = xb;                       j = i; }
    else if (i < NX + NW)     { src = Wq; dst = Wb;                       j = i - NX; }
    else if (i < NX + 2 * NW) { src = Wk; dst = Wb + (size_t)CC * CC;     j = i - NX - NW; }
    else if (i < NX + 3 * NW) { src = Wv; dst = Wb + (size_t)2 * CC * CC; j = i - NX - 2 * NW; }
    else return;
    float4 v = ((const float4*)src)[j];
    u16x4 o;
    o.x = f2bf(v.x); o.y = f2bf(v.y); o.z = f2bf(v.z); o.w = f2bf(v.w);
    ((u16x4*)dst)[j] = o;
}

// ---------------------------------------------------------------- QKV GEMM
// C[m][n] = sum_k x[m][k] * W[n][k]  (+bias, *scale); outputs f16.
// z<2 (Q,K): A=W so each lane holds 4 consecutive d -> 8B stores to [B,H,T,D].
// z==2 (V): A=x so each lane holds 4 consecutive t -> 8B stores into transposed
//           [B,H,D,T] with sigma-permuted key order within each 32-t group:
//           sigma(k) = ((k>>2)&3)*8 + ((k>>4)&1)*4 + (k&3)  (t0%4==0 keeps 4 contiguous)
// Q pre-scaled by (1/sqrt(D)) * log2(e) so attention uses raw exp2.
__global__ void qkv_gemm(const u16* __restrict__ xb, const u16* __restrict__ Wb,
                         const float* __restrict__ bq, const float* __restrict__ bk,
                         const float* __restrict__ bv,
                         u16* __restrict__ Qh, u16* __restrict__ Kh, u16* __restrict__ Vt)
{
    const int z = blockIdx.z;
    const u16* W = Wb + (size_t)z * CC * CC;
    const float* bias = (z == 0) ? bq : ((z == 1) ? bk : bv);
    const float scale = (z == 0) ? 0.18033688011112042f : 1.0f;  // 0.125*log2(e) for Q

    __shared__ __align__(16) u16 As[128][32];   // x rows
    __shared__ __align__(16) u16 Bs[128][32];   // W rows

    const int tid = threadIdx.x;
    const int l  = tid & 63, w = tid >> 6;
    const int wm = w >> 1,  wn = w & 1;
    const int lr = l & 15,  lq = l >> 4;
    const int m0 = blockIdx.y * 128, n0 = blockIdx.x * 128;

    f32x4 acc[4][4] = {};

    // A operand: x for V (z==2), W for Q/K
    const u16* aLDS = (z == 2) ? &As[0][0] : &Bs[0][0];
    const u16* bLDS = (z == 2) ? &Bs[0][0] : &As[0][0];

    for (int kt = 0; kt < CC; kt += 32) {
        __syncthreads();
        #pragma unroll
        for (int r = 0; r < 2; ++r) {
            int c   = (r * 4 + w) * 64 + l;
            int row = c >> 2, kc = c & 3;
            const u16* ga = xb + (size_t)(m0 + row) * CC + kt + kc * 8;
            load_lds16(ga, &As[0][0] + (size_t)c * 8);
            const u16* gb = W + (size_t)(n0 + row) * CC + kt + kc * 8;
            load_lds16(gb, &Bs[0][0] + (size_t)c * 8);
        }
        __syncthreads();

        short8 af[4], bfr[4];
        #pragma unroll
        for (int mi = 0; mi < 4; ++mi)
            af[mi] = *(const short8*)(aLDS + (size_t)(wm * 64 + mi * 16 + lr) * 32 + lq * 8);
        #pragma unroll
        for (int ni = 0; ni < 4; ++ni)
            bfr[ni] = *(const short8*)(bLDS + (size_t)(wn * 64 + ni * 16 + lr) * 32 + lq * 8);
        #pragma unroll
        for (int mi = 0; mi < 4; ++mi)
            #pragma unroll
            for (int ni = 0; ni < 4; ++ni)
                acc[mi][ni] = __builtin_amdgcn_mfma_f32_16x16x32_bf16(
                    af[mi], bfr[ni], acc[mi][ni], 0, 0, 0);
    }

    // epilogue: C/D layout col=lane&15, row=(lane>>4)*4+reg
    if (z == 2) {
        // rows = x (t), cols = W (d). 4 consecutive t per reg group -> sigma slots.
        #pragma unroll
        for (int ni = 0; ni < 4; ++ni) {
            int n = n0 + wn * 64 + ni * 16 + lr;
            float bvv = bias[n];
            int h = n >> 6, d = n & 63;
            #pragma unroll
            for (int mi = 0; mi < 4; ++mi) {
                int mbase = m0 + wm * 64 + mi * 16 + lq * 4;
                int b = mbase >> 11, t0 = mbase & (TT - 1);
                int tg = t0 & ~31;
                int s0 = (((t0 >> 2) & 3) << 3) + (((t0 >> 4) & 1) << 2);
                u16x4 pkv;
                #pragma unroll
                for (int r = 0; r < 4; ++r)
                    pkv[r] = f2h(acc[mi][ni][r] + bvv);
                *(u16x4*)&Vt[((size_t)(b * HH + h) * DD + d) * TT + tg + s0] = pkv;
            }
        }
    } else {
        // rows = W (n -> h,d), cols = x (t). 4 consecutive d per reg group.
        u16* out = (z == 0) ? Qh : Kh;
        #pragma unroll
        for (int mi = 0; mi < 4; ++mi) {
            int nb = n0 + wm * 64 + mi * 16 + lq * 4;
            float4 b4 = *(const float4*)&bias[nb];
            int h = nb >> 6, d0 = nb & 63;
            #pragma unroll
            for (int ni = 0; ni < 4; ++ni) {
                int m = m0 + wn * 64 + ni * 16 + lr;
                int b = m >> 11, t = m & (TT - 1);
                u16x4 pkv;
                pkv.x = f2h((acc[mi][ni][0] + b4.x) * scale);
                pkv.y = f2h((acc[mi][ni][1] + b4.y) * scale);
                pkv.z = f2h((acc[mi][ni][2] + b4.z) * scale);
                pkv.w = f2h((acc[mi][ni][3] + b4.w) * scale);
                *(u16x4*)&out[((size_t)(b * HH + h) * TT + t) * DD + d0] = pkv;
            }
        }
    }
}

// ---------------------------------------------------------------- attention
// 1 block per (b, h, 256 q-rows). 4 waves x 64 q-rows (4 Q-frags). 32-key tiles.
// S computed TRANSPOSED (A=K, B=Q) so exp2(S) per lane is directly the PV A-frag
// under sigma; V pre-permuted in global; K/V staged fully async via
// global_load_lds with XOR-swizzled LDS layouts (lane-linear dest, conflict-free
// frag reads); l computed via MFMA against a constant all-ones B fragment.
__global__ __launch_bounds__(256, 2)
void attn_kernel(const u16* __restrict__ Qh, const u16* __restrict__ Kh,
                 const u16* __restrict__ Vt, const int* __restrict__ mask,
                 float* __restrict__ out)
{
    const int qt = blockIdx.x;   // 0..7
    const int h  = blockIdx.y;   // 0..15
    const int b  = blockIdx.z;   // 0..3
    const int tid = threadIdx.x;
    const int l  = tid & 63, w = tid >> 6;
    const int lr = l & 15,  lq = l >> 4;

    // Swizzled, unpadded (lane-linear for global_load_lds):
    //   K chunk(key,q) at key*8 + (q ^ (key&7)); q = d-chunk 0..7 (8 d each)
    //   V chunk(d,q)   at d*4   + (q ^ ((d>>1)&3)); q = slot-chunk 0..3 (8 slots)
    __shared__ __align__(16) u16 KsL[2][32 * 64];   // 4 KB per buffer
    __shared__ __align__(16) u16 VsL[2][64 * 32];   // 4 KB per buffer

    const size_t base = (size_t)(b * HH + h) * TT * DD;   // TT*DD == DD*TT
    const int q0 = qt * 256 + w * 64;

    // Q B-fragments (f16; 1/sqrt(D)*log2e pre-folded): B[n=q=lr][k=c*32+lq*8+j]
    half8 qf[4][2];
    #pragma unroll
    for (int qg = 0; qg < 4; ++qg)
        #pragma unroll
        for (int c = 0; c < 2; ++c)
            qf[qg][c] = *(const half8*)(Qh + base + (size_t)(q0 + qg * 16 + lr) * DD
                                        + c * 32 + lq * 8);

    // async staging geometry: thread tid stages 16B chunk tid of each tile
    const int kkey = tid >> 3, kqx = tid & 7;
    const int kq = kqx ^ (kkey & 7);
    const u16* kgp = Kh + base + (size_t)kkey * DD + kq * 8;   // + kt*32*DD
    u16* kl0 = &KsL[0][0] + tid * 8;
    const int vdd = tid >> 2, vqx = tid & 3;
    const int vq = vqx ^ ((vdd >> 1) & 3);
    const u16* vgp = Vt + base + (size_t)vdd * TT + vq * 8;    // + kt*32
    u16* vl0 = &VsL[0][0] + tid * 8;

    const int* mbase_p = mask + b * TT + 4 * lq;

    // constant all-ones B fragment for the l (denominator) MFMA
    u32x4 onesbits = { 0x3C003C00u, 0x3C003C00u, 0x3C003C00u, 0x3C003C00u };
    half8 ones = (half8&)onesbits;

    f32x4 o[4][5] = {};   // [qg][dg 0..3 = O d-groups, dg 4 = softmax denom l]

    const int NT = TT / 32;   // 64

    // stage tile 0 -> buffer 0
    load_lds16(kgp, kl0);
    load_lds16(vgp, vl0);
    __syncthreads();

    for (int kt = 0; kt < NT; ++kt) {
        const int p = kt & 1;
        // async-stage next tile into the other buffer (drains at next barrier)
        if (kt + 1 < NT) {
            load_lds16(kgp + (size_t)(kt + 1) * 32 * DD, kl0 + (p ^ 1) * (32 * 64));
            load_lds16(vgp + (size_t)(kt + 1) * 32,      vl0 + (p ^ 1) * (64 * 32));
        }
        int4 ma = *(const int4*)(mbase_p + kt * 32);        // keys 4lq..4lq+3   (kg=0)
        int4 mb = *(const int4*)(mbase_p + kt * 32 + 16);   // keys 16+4lq..+3   (kg=1)

        // ---- K A-fragments: A[m=key=kg*16+lr][k=c*32+lq*8+j], swizzled read
        half8 kf[2][2];
        #pragma unroll
        for (int kg = 0; kg < 2; ++kg) {
            int key = kg * 16 + lr;
            #pragma unroll
            for (int c = 0; c < 2; ++c)
                kf[kg][c] = *(const half8*)&KsL[p][key * 64
                                + (((c * 4 + lq) ^ (key & 7)) * 8)];
        }

        // ---- S^T = K Q^T : lane holds keys kg*16+lq*4+r, q = qg*16+lr
        f32x4 s[2][4];
        #pragma unroll
        for (int kg = 0; kg < 2; ++kg)
            #pragma unroll
            for (int qg = 0; qg < 4; ++qg) {
                f32x4 zz = {};
                zz = __builtin_amdgcn_mfma_f32_16x16x32_f16(kf[kg][0], qf[qg][0], zz, 0, 0, 0);
                zz = __builtin_amdgcn_mfma_f32_16x16x32_f16(kf[kg][1], qf[qg][1], zz, 0, 0, 0);
                s[kg][qg] = zz;
            }

        // ---- P = exp2(S)*mask, packed in-lane into PV A-fragments (sigma layout)
        float f00 = (float)ma.x, f01 = (float)ma.y, f02 = (float)ma.z, f03 = (float)ma.w;
        float f10 = (float)mb.x, f11 = (float)mb.y, f12 = (float)mb.z, f13 = (float)mb.w;
        half8 pf[4];
        #pragma unroll
        for (int qg = 0; qg < 4; ++qg) {
            u32x4 pk;
            pk[0] = pkh(EXP2(s[0][qg][0]) * f00, EXP2(s[0][qg][1]) * f01);
            pk[1] = pkh(EXP2(s[0][qg][2]) * f02, EXP2(s[0][qg][3]) * f03);
            pk[2] = pkh(EXP2(s[1][qg][0]) * f10, EXP2(s[1][qg][1]) * f11);
            pk[3] = pkh(EXP2(s[1][qg][2]) * f12, EXP2(s[1][qg][3]) * f13);
            pf[qg] = (half8&)pk;
        }

        // ---- O += P V  (swizzled V frag reads); l via constant-ones fragment
        #pragma unroll
        for (int dg = 0; dg < 4; ++dg) {
            int d = dg * 16 + lr;
            half8 vf = *(const half8*)&VsL[p][d * 32 + ((lq ^ ((d >> 1) & 3)) * 8)];
            #pragma unroll
            for (int qg = 0; qg < 4; ++qg)
                o[qg][dg] = __builtin_amdgcn_mfma_f32_16x16x32_f16(pf[qg], vf, o[qg][dg], 0, 0, 0);
        }
        #pragma unroll
        for (int qg = 0; qg < 4; ++qg)
            o[qg][4] = __builtin_amdgcn_mfma_f32_16x16x32_f16(pf[qg], ones, o[qg][4], 0, 0, 0);

        __syncthreads();   // drains async loads + all waves done with buffer p
    }

    // ---- epilogue: O / l, write fp32 [B,T,C]
    #pragma unroll
    for (int qg = 0; qg < 4; ++qg)
        #pragma unroll
        for (int r = 0; r < 4; ++r) {
            float inv = 1.f / o[qg][4][r];
            int t = q0 + qg * 16 + lq * 4 + r;
            float* op = out + (size_t)(b * TT + t) * CC + h * DD;
            #pragma unroll
            for (int dg = 0; dg < 4; ++dg)
                op[dg * 16 + lr] = o[qg][dg][r] * inv;
        }
}

// ---------------------------------------------------------------- launch
extern "C" void kernel_launch(void* const* d_in, const int* in_sizes, int n_in,
                              void* d_out, int out_size, void* d_ws, size_t ws_size,
                              hipStream_t stream) {
    const float* x    = (const float*)d_in[0];
    const int*   mask = (const int*)d_in[1];
    const float* Wq   = (const float*)d_in[2];
    const float* bq   = (const float*)d_in[3];
    const float* Wk   = (const float*)d_in[4];
    const float* bk   = (const float*)d_in[5];
    const float* Wv   = (const float*)d_in[6];
    const float* bv   = (const float*)d_in[7];
    float* out = (float*)d_out;

    // workspace layout
    u16* xb = (u16*)d_ws;                              // bf16 [8192][1024]
    u16* Wb = xb + (size_t)MM * CC;                    // bf16 [3][1024][1024]
    u16* Qh = Wb + (size_t)3 * CC * CC;                // f16 [B,H,T,D]
    u16* Kh = Qh + (size_t)MM * CC;                    // f16 [B,H,T,D]
    u16* Vt = Kh + (size_t)MM * CC;                    // f16 [B,H,D,T], sigma key order

    {
        int total = NX + 3 * NW;
        cvt_all<<<(total + 255) / 256, 256, 0, stream>>>(x, Wq, Wk, Wv, xb, Wb);
    }

    qkv_gemm<<<dim3(CC / 128, MM / 128, 3), 256, 0, stream>>>(xb, Wb, bq, bk, bv, Qh, Kh, Vt);

    attn_kernel<<<dim3(TT / 256, HH, BB), 256, 0, stream>>>(Qh, Kh, Vt, mask, out);
}

// Round 7
// 254.200 us; speedup vs baseline: 1.0079x; 1.0079x over previous
//
#include <hip/hip_runtime.h>
#include <stdint.h>

// Problem constants
#define BB 4
#define TT 2048
#define CC 1024
#define HH 16
#define DD 64
#define MM (BB * TT)   // 8192 rows for QKV projection

typedef unsigned short u16;
typedef unsigned int   u32;
typedef __attribute__((ext_vector_type(8))) short short8;   // 8 bf16 (4 VGPRs)
typedef _Float16 half8  __attribute__((ext_vector_type(8)));
typedef __fp16   fp16x2 __attribute__((ext_vector_type(2)));
typedef __attribute__((ext_vector_type(4))) float f32x4;    // MFMA C/D
typedef __attribute__((ext_vector_type(4))) unsigned short u16x4;
typedef __attribute__((ext_vector_type(4))) unsigned int u32x4;

#if __has_builtin(__builtin_amdgcn_exp2f)
#define EXP2(x) __builtin_amdgcn_exp2f(x)
#else
#define EXP2(x) __expf(0.69314718055994531f * (x))
#endif

__device__ inline u16 f2bf(float f) {
    union { float f; unsigned u; } v; v.f = f;
    unsigned r = 0x7fffu + ((v.u >> 16) & 1u);   // RNE
    return (u16)((v.u + r) >> 16);
}
__device__ inline u16 f2h(float f) {
    union { _Float16 h; u16 u; } c; c.h = (_Float16)f; return c.u;
}
__device__ inline u32 pkh(float a, float b) {   // pack 2 f32 -> f16x2 (v_cvt_pkrtz)
    union { fp16x2 h; u32 u; } c;
    c.h = __builtin_amdgcn_cvt_pkrtz(a, b);
    return c.u;
}
__device__ inline void load_lds16(const u16* g, u16* l) {
    __builtin_amdgcn_global_load_lds((const __attribute__((address_space(1))) void*)g,
                                     (__attribute__((address_space(3))) void*)l, 16, 0, 0);
}

// ---------------------------------------------------------------- convert (fused)
#define NX (MM * CC / 4)   // x float4 count
#define NW (CC * CC / 4)   // one W float4 count
__global__ void cvt_all(const float* __restrict__ x,  const float* __restrict__ Wq,
                        const float* __restrict__ Wk, const float* __restrict__ Wv,
                        u16* __restrict__ xb, u16* __restrict__ Wb) {
    int i = blockIdx.x * blockDim.x + threadIdx.x;
    const float* src; u16* dst; int j;
    if (i < NX)               { src = x;  dst = xb;                       j = i; }
    else if (i < NX + NW)     { src = Wq; dst = Wb;                       j = i - NX; }
    else if (i < NX + 2 * NW) { src = Wk; dst = Wb + (size_t)CC * CC;     j = i - NX - NW; }
    else if (i < NX + 3 * NW) { src = Wv; dst = Wb + (size_t)2 * CC * CC; j = i - NX - 2 * NW; }
    else return;
    float4 v = ((const float4*)src)[j];
    u16x4 o;
    o.x = f2bf(v.x); o.y = f2bf(v.y); o.z = f2bf(v.z); o.w = f2bf(v.w);
    ((u16x4*)dst)[j] = o;
}

// ---------------------------------------------------------------- QKV GEMM
// C[m][n] = sum_k x[m][k] * W[n][k]  (+bias, *scale); outputs f16.
// z<2 (Q,K): A=W so each lane holds 4 consecutive d -> 8B stores to [B,H,T,D].
// z==2 (V): A=x so each lane holds 4 consecutive t -> 8B stores into transposed
//           [B,H,D,T] with sigma-permuted key order within each 32-t group:
//           sigma(k) = ((k>>2)&3)*8 + ((k>>4)&1)*4 + (k&3)
// Q pre-scaled by (1/sqrt(D)) * log2(e) so attention uses raw exp2.
__global__ void qkv_gemm(const u16* __restrict__ xb, const u16* __restrict__ Wb,
                         const float* __restrict__ bq, const float* __restrict__ bk,
                         const float* __restrict__ bv,
                         u16* __restrict__ Qh, u16* __restrict__ Kh, u16* __restrict__ Vt)
{
    const int z = blockIdx.z;
    const u16* W = Wb + (size_t)z * CC * CC;
    const float* bias = (z == 0) ? bq : ((z == 1) ? bk : bv);
    const float scale = (z == 0) ? 0.18033688011112042f : 1.0f;  // 0.125*log2(e) for Q

    __shared__ __align__(16) u16 As[128][32];   // x rows
    __shared__ __align__(16) u16 Bs[128][32];   // W rows

    const int tid = threadIdx.x;
    const int l  = tid & 63, w = tid >> 6;
    const int wm = w >> 1,  wn = w & 1;
    const int lr = l & 15,  lq = l >> 4;
    const int m0 = blockIdx.y * 128, n0 = blockIdx.x * 128;

    f32x4 acc[4][4] = {};

    // A operand: x for V (z==2), W for Q/K
    const u16* aLDS = (z == 2) ? &As[0][0] : &Bs[0][0];
    const u16* bLDS = (z == 2) ? &Bs[0][0] : &As[0][0];

    for (int kt = 0; kt < CC; kt += 32) {
        __syncthreads();
        #pragma unroll
        for (int r = 0; r < 2; ++r) {
            int c   = (r * 4 + w) * 64 + l;
            int row = c >> 2, kc = c & 3;
            const u16* ga = xb + (size_t)(m0 + row) * CC + kt + kc * 8;
            load_lds16(ga, &As[0][0] + (size_t)c * 8);
            const u16* gb = W + (size_t)(n0 + row) * CC + kt + kc * 8;
            load_lds16(gb, &Bs[0][0] + (size_t)c * 8);
        }
        __syncthreads();

        short8 af[4], bfr[4];
        #pragma unroll
        for (int mi = 0; mi < 4; ++mi)
            af[mi] = *(const short8*)(aLDS + (size_t)(wm * 64 + mi * 16 + lr) * 32 + lq * 8);
        #pragma unroll
        for (int ni = 0; ni < 4; ++ni)
            bfr[ni] = *(const short8*)(bLDS + (size_t)(wn * 64 + ni * 16 + lr) * 32 + lq * 8);
        #pragma unroll
        for (int mi = 0; mi < 4; ++mi)
            #pragma unroll
            for (int ni = 0; ni < 4; ++ni)
                acc[mi][ni] = __builtin_amdgcn_mfma_f32_16x16x32_bf16(
                    af[mi], bfr[ni], acc[mi][ni], 0, 0, 0);
    }

    // epilogue: C/D layout col=lane&15, row=(lane>>4)*4+reg
    if (z == 2) {
        // rows = x (t), cols = W (d). 4 consecutive t per reg group -> sigma slots.
        #pragma unroll
        for (int ni = 0; ni < 4; ++ni) {
            int n = n0 + wn * 64 + ni * 16 + lr;
            float bvv = bias[n];
            int h = n >> 6, d = n & 63;
            #pragma unroll
            for (int mi = 0; mi < 4; ++mi) {
                int mbase = m0 + wm * 64 + mi * 16 + lq * 4;
                int b = mbase >> 11, t0 = mbase & (TT - 1);
                int tg = t0 & ~31;
                int s0 = (((t0 >> 2) & 3) << 3) + (((t0 >> 4) & 1) << 2);
                u16x4 pkv;
                #pragma unroll
                for (int r = 0; r < 4; ++r)
                    pkv[r] = f2h(acc[mi][ni][r] + bvv);
                *(u16x4*)&Vt[((size_t)(b * HH + h) * DD + d) * TT + tg + s0] = pkv;
            }
        }
    } else {
        // rows = W (n -> h,d), cols = x (t). 4 consecutive d per reg group.
        u16* out = (z == 0) ? Qh : Kh;
        #pragma unroll
        for (int mi = 0; mi < 4; ++mi) {
            int nb = n0 + wm * 64 + mi * 16 + lq * 4;
            float4 b4 = *(const float4*)&bias[nb];
            int h = nb >> 6, d0 = nb & 63;
            #pragma unroll
            for (int ni = 0; ni < 4; ++ni) {
                int m = m0 + wn * 64 + ni * 16 + lr;
                int b = m >> 11, t = m & (TT - 1);
                u16x4 pkv;
                pkv.x = f2h((acc[mi][ni][0] + b4.x) * scale);
                pkv.y = f2h((acc[mi][ni][1] + b4.y) * scale);
                pkv.z = f2h((acc[mi][ni][2] + b4.z) * scale);
                pkv.w = f2h((acc[mi][ni][3] + b4.w) * scale);
                *(u16x4*)&out[((size_t)(b * HH + h) * TT + t) * DD + d0] = pkv;
            }
        }
    }
}

// ---------------------------------------------------------------- attention
// Grid (x=h, y=qt, z=b): XCD = linear_block_id & 7 = h & 7, so all q-tile
// blocks sharing one (b,h)'s K/V cluster on one XCD -> K/V re-reads hit L2.
// 1 block per (b, h, 128 q-rows). 4 waves x 32 q-rows (2 Q-frags). 32-key tiles.
// S computed transposed (A=K, B=Q) so exp2(S) per lane is directly the PV A-frag
// under sigma; V pre-permuted in global; K/V staged async via global_load_lds
// with XOR-swizzled LDS (conflict-free, verified r6: SQ_LDS_BANK_CONFLICT=0);
// l via MFMA against a constant all-ones B fragment.
__global__ __launch_bounds__(256, 4)
void attn_kernel(const u16* __restrict__ Qh, const u16* __restrict__ Kh,
                 const u16* __restrict__ Vt, const int* __restrict__ mask,
                 float* __restrict__ out)
{
    const int h  = blockIdx.x;   // 0..15  (XCD affinity)
    const int qt = blockIdx.y;   // 0..15
    const int b  = blockIdx.z;   // 0..3
    const int tid = threadIdx.x;
    const int l  = tid & 63, w = tid >> 6;
    const int lr = l & 15,  lq = l >> 4;

    // Swizzled, unpadded (lane-linear for global_load_lds):
    //   K chunk(key,q) at key*8 + (q ^ (key&7)); q = d-chunk 0..7
    //   V chunk(d,q)   at d*4   + (q ^ ((d>>1)&3)); q = slot-chunk 0..3
    __shared__ __align__(16) u16 KsL[2][32 * 64];   // 4 KB per buffer
    __shared__ __align__(16) u16 VsL[2][64 * 32];   // 4 KB per buffer

    const size_t base = (size_t)(b * HH + h) * TT * DD;   // TT*DD == DD*TT
    const int q0 = qt * 128 + w * 32;

    // Q B-fragments (f16; 1/sqrt(D)*log2e pre-folded): B[n=q=lr][k=c*32+lq*8+j]
    half8 qf[2][2];
    #pragma unroll
    for (int qg = 0; qg < 2; ++qg)
        #pragma unroll
        for (int c = 0; c < 2; ++c)
            qf[qg][c] = *(const half8*)(Qh + base + (size_t)(q0 + qg * 16 + lr) * DD
                                        + c * 32 + lq * 8);

    // async staging geometry: thread tid stages 16B chunk tid of each tile
    const int kkey = tid >> 3, kqx = tid & 7;
    const int kq = kqx ^ (kkey & 7);
    const u16* kgp = Kh + base + (size_t)kkey * DD + kq * 8;   // + kt*32*DD
    u16* kl0 = &KsL[0][0] + tid * 8;
    const int vdd = tid >> 2, vqx = tid & 3;
    const int vq = vqx ^ ((vdd >> 1) & 3);
    const u16* vgp = Vt + base + (size_t)vdd * TT + vq * 8;    // + kt*32
    u16* vl0 = &VsL[0][0] + tid * 8;

    const int* mbase_p = mask + b * TT + 4 * lq;

    // constant all-ones B fragment for the l (denominator) MFMA
    u32x4 onesbits = { 0x3C003C00u, 0x3C003C00u, 0x3C003C00u, 0x3C003C00u };
    half8 ones = (half8&)onesbits;

    f32x4 o[2][5] = {};   // [qg][dg 0..3 = O d-groups, dg 4 = softmax denom l]

    const int NT = TT / 32;   // 64

    // stage tile 0 -> buffer 0
    load_lds16(kgp, kl0);
    load_lds16(vgp, vl0);
    __syncthreads();

    for (int kt = 0; kt < NT; ++kt) {
        const int p = kt & 1;
        // async-stage next tile into the other buffer (drains at next barrier)
        if (kt + 1 < NT) {
            load_lds16(kgp + (size_t)(kt + 1) * 32 * DD, kl0 + (p ^ 1) * (32 * 64));
            load_lds16(vgp + (size_t)(kt + 1) * 32,      vl0 + (p ^ 1) * (64 * 32));
        }
        int4 ma = *(const int4*)(mbase_p + kt * 32);        // keys 4lq..4lq+3   (kg=0)
        int4 mb = *(const int4*)(mbase_p + kt * 32 + 16);   // keys 16+4lq..+3   (kg=1)

        // ---- K A-fragments: A[m=key=kg*16+lr][k=c*32+lq*8+j], swizzled read
        half8 kf[2][2];
        #pragma unroll
        for (int kg = 0; kg < 2; ++kg) {
            int key = kg * 16 + lr;
            #pragma unroll
            for (int c = 0; c < 2; ++c)
                kf[kg][c] = *(const half8*)&KsL[p][key * 64
                                + (((c * 4 + lq) ^ (key & 7)) * 8)];
        }

        // ---- S^T = K Q^T : lane holds keys kg*16+lq*4+r, q = qg*16+lr
        f32x4 s[2][2];
        #pragma unroll
        for (int kg = 0; kg < 2; ++kg)
            #pragma unroll
            for (int qg = 0; qg < 2; ++qg) {
                f32x4 zz = {};
                zz = __builtin_amdgcn_mfma_f32_16x16x32_f16(kf[kg][0], qf[qg][0], zz, 0, 0, 0);
                zz = __builtin_amdgcn_mfma_f32_16x16x32_f16(kf[kg][1], qf[qg][1], zz, 0, 0, 0);
                s[kg][qg] = zz;
            }

        // ---- P = exp2(S)*mask, packed in-lane into PV A-fragments (sigma layout)
        float f00 = (float)ma.x, f01 = (float)ma.y, f02 = (float)ma.z, f03 = (float)ma.w;
        float f10 = (float)mb.x, f11 = (float)mb.y, f12 = (float)mb.z, f13 = (float)mb.w;
        half8 pf[2];
        #pragma unroll
        for (int qg = 0; qg < 2; ++qg) {
            u32x4 pk;
            pk[0] = pkh(EXP2(s[0][qg][0]) * f00, EXP2(s[0][qg][1]) * f01);
            pk[1] = pkh(EXP2(s[0][qg][2]) * f02, EXP2(s[0][qg][3]) * f03);
            pk[2] = pkh(EXP2(s[1][qg][0]) * f10, EXP2(s[1][qg][1]) * f11);
            pk[3] = pkh(EXP2(s[1][qg][2]) * f12, EXP2(s[1][qg][3]) * f13);
            pf[qg] = (half8&)pk;
        }

        // ---- O += P V  (swizzled V frag reads); l via constant-ones fragment
        #pragma unroll
        for (int dg = 0; dg < 4; ++dg) {
            int d = dg * 16 + lr;
            half8 vf = *(const half8*)&VsL[p][d * 32 + ((lq ^ ((d >> 1) & 3)) * 8)];
            #pragma unroll
            for (int qg = 0; qg < 2; ++qg)
                o[qg][dg] = __builtin_amdgcn_mfma_f32_16x16x32_f16(pf[qg], vf, o[qg][dg], 0, 0, 0);
        }
        #pragma unroll
        for (int qg = 0; qg < 2; ++qg)
            o[qg][4] = __builtin_amdgcn_mfma_f32_16x16x32_f16(pf[qg], ones, o[qg][4], 0, 0, 0);

        __syncthreads();   // drains async loads + all waves done with buffer p
    }

    // ---- epilogue: O / l, write fp32 [B,T,C]
    #pragma unroll
    for (int qg = 0; qg < 2; ++qg)
        #pragma unroll
        for (int r = 0; r < 4; ++r) {
            float inv = 1.f / o[qg][4][r];
            int t = q0 + qg * 16 + lq * 4 + r;
            float* op = out + (size_t)(b * TT + t) * CC + h * DD;
            #pragma unroll
            for (int dg = 0; dg < 4; ++dg)
                op[dg * 16 + lr] = o[qg][dg][r] * inv;
        }
}

// ---------------------------------------------------------------- launch
extern "C" void kernel_launch(void* const* d_in, const int* in_sizes, int n_in,
                              void* d_out, int out_size, void* d_ws, size_t ws_size,
                              hipStream_t stream) {
    const float* x    = (const float*)d_in[0];
    const int*   mask = (const int*)d_in[1];
    const float* Wq   = (const float*)d_in[2];
    const float* bq   = (const float*)d_in[3];
    const float* Wk   = (const float*)d_in[4];
    const float* bk   = (const float*)d_in[5];
    const float* Wv   = (const float*)d_in[6];
    const float* bv   = (const float*)d_in[7];
    float* out = (float*)d_out;

    // workspace layout
    u16* xb = (u16*)d_ws;                              // bf16 [8192][1024]
    u16* Wb = xb + (size_t)MM * CC;                    // bf16 [3][1024][1024]
    u16* Qh = Wb + (size_t)3 * CC * CC;                // f16 [B,H,T,D]
    u16* Kh = Qh + (size_t)MM * CC;                    // f16 [B,H,T,D]
    u16* Vt = Kh + (size_t)MM * CC;                    // f16 [B,H,D,T], sigma key order

    {
        int total = NX + 3 * NW;
        cvt_all<<<(total + 255) / 256, 256, 0, stream>>>(x, Wq, Wk, Wv, xb, Wb);
    }

    qkv_gemm<<<dim3(CC / 128, MM / 128, 3), 256, 0, stream>>>(xb, Wb, bq, bk, bv, Qh, Kh, Vt);

    // grid: x=h (XCD affinity), y=q-tile, z=b
    attn_kernel<<<dim3(HH, TT / 128, BB), 256, 0, stream>>>(Qh, Kh, Vt, mask, out);
}

// Round 8
// 253.445 us; speedup vs baseline: 1.0109x; 1.0030x over previous
//
#include <hip/hip_runtime.h>
#include <stdint.h>

// Problem constants
#define BB 4
#define TT 2048
#define CC 1024
#define HH 16
#define DD 64
#define MM (BB * TT)   // 8192 rows for QKV projection

typedef unsigned short u16;
typedef unsigned int   u32;
typedef __attribute__((ext_vector_type(8))) short short8;   // 8 bf16 (4 VGPRs)
typedef _Float16 half8  __attribute__((ext_vector_type(8)));
typedef __fp16   fp16x2 __attribute__((ext_vector_type(2)));
typedef __attribute__((ext_vector_type(4))) float f32x4;    // MFMA C/D
typedef __attribute__((ext_vector_type(4))) unsigned short u16x4;
typedef __attribute__((ext_vector_type(4))) unsigned int u32x4;

#if __has_builtin(__builtin_amdgcn_exp2f)
#define EXP2(x) __builtin_amdgcn_exp2f(x)
#else
#define EXP2(x) __expf(0.69314718055994531f * (x))
#endif

__device__ inline u16 f2bf(float f) {
    union { float f; unsigned u; } v; v.f = f;
    unsigned r = 0x7fffu + ((v.u >> 16) & 1u);   // RNE
    return (u16)((v.u + r) >> 16);
}
__device__ inline u16 f2h(float f) {
    union { _Float16 h; u16 u; } c; c.h = (_Float16)f; return c.u;
}
__device__ inline u32 pkh(float a, float b) {   // pack 2 f32 -> f16x2 (v_cvt_pkrtz)
    union { fp16x2 h; u32 u; } c;
    c.h = __builtin_amdgcn_cvt_pkrtz(a, b);
    return c.u;
}
__device__ inline void load_lds16(const u16* g, u16* l) {
    __builtin_amdgcn_global_load_lds((const __attribute__((address_space(1))) void*)g,
                                     (__attribute__((address_space(3))) void*)l, 16, 0, 0);
}

// ---------------------------------------------------------------- convert (fused)
#define NX (MM * CC / 4)   // x float4 count
#define NW (CC * CC / 4)   // one W float4 count
#define NM (BB * TT / 4)   // mask int4 count
__global__ void cvt_all(const float* __restrict__ x,  const float* __restrict__ Wq,
                        const float* __restrict__ Wk, const float* __restrict__ Wv,
                        const int* __restrict__ mask,
                        u16* __restrict__ xb, u16* __restrict__ Wb, float* __restrict__ fm) {
    int i = blockIdx.x * blockDim.x + threadIdx.x;
    if (i >= NX + 3 * NW) {
        int j = i - (NX + 3 * NW);
        if (j < NM) {
            int4 mm = ((const int4*)mask)[j];
            float4 o = { (float)mm.x, (float)mm.y, (float)mm.z, (float)mm.w };
            ((float4*)fm)[j] = o;
        }
        return;
    }
    const float* src; u16* dst; int j;
    if (i < NX)               { src = x;  dst = xb;                       j = i; }
    else if (i < NX + NW)     { src = Wq; dst = Wb;                       j = i - NX; }
    else if (i < NX + 2 * NW) { src = Wk; dst = Wb + (size_t)CC * CC;     j = i - NX - NW; }
    else                      { src = Wv; dst = Wb + (size_t)2 * CC * CC; j = i - NX - 2 * NW; }
    float4 v = ((const float4*)src)[j];
    u16x4 o;
    o.x = f2bf(v.x); o.y = f2bf(v.y); o.z = f2bf(v.z); o.w = f2bf(v.w);
    ((u16x4*)dst)[j] = o;
}

// ---------------------------------------------------------------- QKV GEMM
// BK=64 (16 K-iters, 32 MFMA each), XOR-swizzled LDS columns (swizzle applied on
// the GLOBAL address side; LDS dest stays lane-linear per global_load_lds rules).
// Fragment reads: bank quad = f(row&7 ^ chunk) -> 2-way only (free).
// z<2 (Q,K): A=W so each lane holds 4 consecutive d -> 8B stores to [B,H,T,D].
// z==2 (V): A=x so each lane holds 4 consecutive t -> 8B stores into transposed
//           [B,H,D,T] with sigma-permuted key order within each 32-t group.
// Q pre-scaled by (1/sqrt(D)) * log2(e) so attention uses raw exp2.
__global__ void qkv_gemm(const u16* __restrict__ xb, const u16* __restrict__ Wb,
                         const float* __restrict__ bq, const float* __restrict__ bk,
                         const float* __restrict__ bv,
                         u16* __restrict__ Qh, u16* __restrict__ Kh, u16* __restrict__ Vt)
{
    const int z = blockIdx.z;
    const u16* W = Wb + (size_t)z * CC * CC;
    const float* bias = (z == 0) ? bq : ((z == 1) ? bk : bv);
    const float scale = (z == 0) ? 0.18033688011112042f : 1.0f;  // 0.125*log2(e) for Q

    __shared__ __align__(16) u16 As[128 * 64];   // 16 KB, swizzled columns
    __shared__ __align__(16) u16 Bs[128 * 64];

    const int tid = threadIdx.x;
    const int l  = tid & 63, w = tid >> 6;
    const int wm = w >> 1,  wn = w & 1;
    const int lr = l & 15,  lq = l >> 4;
    const int m0 = blockIdx.y * 128, n0 = blockIdx.x * 128;

    f32x4 acc[4][4] = {};

    const u16* aLDS = (z == 2) ? As : Bs;
    const u16* bLDS = (z == 2) ? Bs : As;

    for (int kt = 0; kt < CC; kt += 64) {
        __syncthreads();
        #pragma unroll
        for (int r = 0; r < 4; ++r) {
            int c   = r * 256 + tid;           // physical 16B chunk 0..1023
            int row = c >> 3, q = c & 7;
            int kc  = q ^ (row & 7);           // global column chunk (swizzle)
            load_lds16(xb + (size_t)(m0 + row) * CC + kt + kc * 8, As + (size_t)c * 8);
            load_lds16(W  + (size_t)(n0 + row) * CC + kt + kc * 8, Bs + (size_t)c * 8);
        }
        __syncthreads();

        #pragma unroll
        for (int s = 0; s < 2; ++s) {
            short8 af[4], bfr[4];
            #pragma unroll
            for (int mi = 0; mi < 4; ++mi) {
                int row = wm * 64 + mi * 16 + lr;
                af[mi] = *(const short8*)(aLDS + (size_t)row * 64
                                          + (((s * 4 + lq) ^ (row & 7)) * 8));
            }
            #pragma unroll
            for (int ni = 0; ni < 4; ++ni) {
                int row = wn * 64 + ni * 16 + lr;
                bfr[ni] = *(const short8*)(bLDS + (size_t)row * 64
                                           + (((s * 4 + lq) ^ (row & 7)) * 8));
            }
            #pragma unroll
            for (int mi = 0; mi < 4; ++mi)
                #pragma unroll
                for (int ni = 0; ni < 4; ++ni)
                    acc[mi][ni] = __builtin_amdgcn_mfma_f32_16x16x32_bf16(
                        af[mi], bfr[ni], acc[mi][ni], 0, 0, 0);
        }
    }

    // epilogue: C/D layout col=lane&15, row=(lane>>4)*4+reg
    if (z == 2) {
        #pragma unroll
        for (int ni = 0; ni < 4; ++ni) {
            int n = n0 + wn * 64 + ni * 16 + lr;
            float bvv = bias[n];
            int h = n >> 6, d = n & 63;
            #pragma unroll
            for (int mi = 0; mi < 4; ++mi) {
                int mbase = m0 + wm * 64 + mi * 16 + lq * 4;
                int b = mbase >> 11, t0 = mbase & (TT - 1);
                int tg = t0 & ~31;
                int s0 = (((t0 >> 2) & 3) << 3) + (((t0 >> 4) & 1) << 2);
                u16x4 pkv;
                #pragma unroll
                for (int r = 0; r < 4; ++r)
                    pkv[r] = f2h(acc[mi][ni][r] + bvv);
                *(u16x4*)&Vt[((size_t)(b * HH + h) * DD + d) * TT + tg + s0] = pkv;
            }
        }
    } else {
        u16* out = (z == 0) ? Qh : Kh;
        #pragma unroll
        for (int mi = 0; mi < 4; ++mi) {
            int nb = n0 + wm * 64 + mi * 16 + lq * 4;
            float4 b4 = *(const float4*)&bias[nb];
            int h = nb >> 6, d0 = nb & 63;
            #pragma unroll
            for (int ni = 0; ni < 4; ++ni) {
                int m = m0 + wn * 64 + ni * 16 + lr;
                int b = m >> 11, t = m & (TT - 1);
                u16x4 pkv;
                pkv.x = f2h((acc[mi][ni][0] + b4.x) * scale);
                pkv.y = f2h((acc[mi][ni][1] + b4.y) * scale);
                pkv.z = f2h((acc[mi][ni][2] + b4.z) * scale);
                pkv.w = f2h((acc[mi][ni][3] + b4.w) * scale);
                *(u16x4*)&out[((size_t)(b * HH + h) * TT + t) * DD + d0] = pkv;
            }
        }
    }
}

// ---------------------------------------------------------------- attention
// Grid (x=h, y=qt, z=b): XCD = h&7 (r7-verified: FETCH 139->25 MB).
// 1 block per (b, h, 256 q). 4 waves x 64 q (4 Q-frags). 64-key double-buffered
// tiles (two 32-key subtiles), async global_load_lds staging, XOR swizzles
// (r6/r7-verified conflict-free), sigma in-lane S->P->PV (no P LDS round-trip),
// l via constant-ones B fragment, float mask precomputed.
__global__ __launch_bounds__(256, 2)
void attn_kernel(const u16* __restrict__ Qh, const u16* __restrict__ Kh,
                 const u16* __restrict__ Vt, const float* __restrict__ fm,
                 float* __restrict__ out)
{
    const int h  = blockIdx.x;   // 0..15  (XCD affinity)
    const int qt = blockIdx.y;   // 0..7
    const int b  = blockIdx.z;   // 0..3
    const int tid = threadIdx.x;
    const int l  = tid & 63, w = tid >> 6;
    const int lr = l & 15,  lq = l >> 4;

    // per buffer: [sub 0..1][key 0..31][d-chunks swizzled] / [sub][d][slot-chunks]
    __shared__ __align__(16) u16 KsL[2][4096];   // 8 KB per buffer
    __shared__ __align__(16) u16 VsL[2][4096];   // 8 KB per buffer

    const size_t base = (size_t)(b * HH + h) * TT * DD;   // TT*DD == DD*TT
    const int q0 = qt * 256 + w * 64;

    // Q B-fragments (f16; 1/sqrt(D)*log2e pre-folded): B[n=q=lr][k=c*32+lq*8+j]
    half8 qf[4][2];
    #pragma unroll
    for (int qg = 0; qg < 4; ++qg)
        #pragma unroll
        for (int c = 0; c < 2; ++c)
            qf[qg][c] = *(const half8*)(Qh + base + (size_t)(q0 + qg * 16 + lr) * DD
                                        + c * 32 + lq * 8);

    // async staging geometry (thread t stages chunk t of each 32-key subtile)
    const int kkey = tid >> 3, kqx = tid & 7;
    const int kq = kqx ^ (kkey & 7);
    const u16* kgp = Kh + base + (size_t)kkey * DD + kq * 8;   // +kt*64*DD; sub1 +32*DD
    u16* kl = &KsL[0][0] + tid * 8;
    const int vdd = tid >> 2, vqx = tid & 3;
    const int vq = vqx ^ ((vdd >> 1) & 3);
    const u16* vgp = Vt + base + (size_t)vdd * TT + vq * 8;    // +kt*64; sub1 +32
    u16* vl = &VsL[0][0] + tid * 8;

    const float* fmp = fm + b * TT + 4 * lq;

    u32x4 onesbits = { 0x3C003C00u, 0x3C003C00u, 0x3C003C00u, 0x3C003C00u };
    half8 ones = (half8&)onesbits;

    f32x4 o[4][5] = {};   // [qg][dg 0..3 = O d-groups, dg 4 = softmax denom l]

    const int NT = TT / 64;   // 32

    // stage tile 0 -> buffer 0
    load_lds16(kgp,            kl);
    load_lds16(kgp + 32 * DD,  kl + 2048);
    load_lds16(vgp,            vl);
    load_lds16(vgp + 32,       vl + 2048);
    __syncthreads();

    for (int kt = 0; kt < NT; ++kt) {
        const int p = kt & 1;
        if (kt + 1 < NT) {   // async-stage next tile (drains at next barrier)
            const u16* kg2 = kgp + (size_t)(kt + 1) * 64 * DD;
            const u16* vg2 = vgp + (kt + 1) * 64;
            load_lds16(kg2,           kl + (p ^ 1) * 4096);
            load_lds16(kg2 + 32 * DD, kl + (p ^ 1) * 4096 + 2048);
            load_lds16(vg2,           vl + (p ^ 1) * 4096);
            load_lds16(vg2 + 32,      vl + (p ^ 1) * 4096 + 2048);
        }
        const u16* Kp = &KsL[0][0] + p * 4096;
        const u16* Vp = &VsL[0][0] + p * 4096;

        half8 pf[4][2];
        #pragma unroll
        for (int sub = 0; sub < 2; ++sub) {
            // K A-frags: keys sub*32 + {lr, 16+lr}; (16+lr)&7 == lr&7
            half8 kf0[2], kf1[2];
            #pragma unroll
            for (int c = 0; c < 2; ++c) {
                int sw = ((c * 4 + lq) ^ (lr & 7)) * 8;
                kf0[c] = *(const half8*)(Kp + sub * 2048 + (size_t)lr * 64 + sw);
                kf1[c] = *(const half8*)(Kp + sub * 2048 + (size_t)(16 + lr) * 64 + sw);
            }
            // S^T = K Q^T : lane holds keys sub*32 + kgl*16 + lq*4 + r, q = qg*16+lr
            f32x4 s0[4], s1[4];
            #pragma unroll
            for (int qg = 0; qg < 4; ++qg) {
                f32x4 z0 = {}, z1 = {};
                z0 = __builtin_amdgcn_mfma_f32_16x16x32_f16(kf0[0], qf[qg][0], z0, 0, 0, 0);
                z0 = __builtin_amdgcn_mfma_f32_16x16x32_f16(kf0[1], qf[qg][1], z0, 0, 0, 0);
                z1 = __builtin_amdgcn_mfma_f32_16x16x32_f16(kf1[0], qf[qg][0], z1, 0, 0, 0);
                z1 = __builtin_amdgcn_mfma_f32_16x16x32_f16(kf1[1], qf[qg][1], z1, 0, 0, 0);
                s0[qg] = z0; s1[qg] = z1;
            }
            // P = exp2(S)*mask, packed in-lane into PV A-frag (sigma layout)
            float4 fa = *(const float4*)(fmp + kt * 64 + sub * 32);
            float4 fb = *(const float4*)(fmp + kt * 64 + sub * 32 + 16);
            #pragma unroll
            for (int qg = 0; qg < 4; ++qg) {
                u32x4 pk;
                pk[0] = pkh(EXP2(s0[qg][0]) * fa.x, EXP2(s0[qg][1]) * fa.y);
                pk[1] = pkh(EXP2(s0[qg][2]) * fa.z, EXP2(s0[qg][3]) * fa.w);
                pk[2] = pkh(EXP2(s1[qg][0]) * fb.x, EXP2(s1[qg][1]) * fb.y);
                pk[3] = pkh(EXP2(s1[qg][2]) * fb.z, EXP2(s1[qg][3]) * fb.w);
                pf[qg][sub] = (half8&)pk;
            }
        }

        // O += P V (swizzled V frag reads; two 32-key sub-chains)
        #pragma unroll
        for (int dg = 0; dg < 4; ++dg) {
            int d = dg * 16 + lr;
            int sw = ((lq ^ ((d >> 1) & 3)) * 8);
            half8 vf0 = *(const half8*)(Vp + (size_t)d * 32 + sw);
            half8 vf1 = *(const half8*)(Vp + 2048 + (size_t)d * 32 + sw);
            #pragma unroll
            for (int qg = 0; qg < 4; ++qg) {
                o[qg][dg] = __builtin_amdgcn_mfma_f32_16x16x32_f16(pf[qg][0], vf0, o[qg][dg], 0, 0, 0);
                o[qg][dg] = __builtin_amdgcn_mfma_f32_16x16x32_f16(pf[qg][1], vf1, o[qg][dg], 0, 0, 0);
            }
        }
        #pragma unroll
        for (int qg = 0; qg < 4; ++qg) {
            o[qg][4] = __builtin_amdgcn_mfma_f32_16x16x32_f16(pf[qg][0], ones, o[qg][4], 0, 0, 0);
            o[qg][4] = __builtin_amdgcn_mfma_f32_16x16x32_f16(pf[qg][1], ones, o[qg][4], 0, 0, 0);
        }

        __syncthreads();   // drains async loads + all waves done with buffer p
    }

    // ---- epilogue: O / l, write fp32 [B,T,C]
    #pragma unroll
    for (int qg = 0; qg < 4; ++qg)
        #pragma unroll
        for (int r = 0; r < 4; ++r) {
            float inv = 1.f / o[qg][4][r];
            int t = q0 + qg * 16 + lq * 4 + r;
            float* op = out + (size_t)(b * TT + t) * CC + h * DD;
            #pragma unroll
            for (int dg = 0; dg < 4; ++dg)
                op[dg * 16 + lr] = o[qg][dg][r] * inv;
        }
}

// ---------------------------------------------------------------- launch
extern "C" void kernel_launch(void* const* d_in, const int* in_sizes, int n_in,
                              void* d_out, int out_size, void* d_ws, size_t ws_size,
                              hipStream_t stream) {
    const float* x    = (const float*)d_in[0];
    const int*   mask = (const int*)d_in[1];
    const float* Wq   = (const float*)d_in[2];
    const float* bq   = (const float*)d_in[3];
    const float* Wk   = (const float*)d_in[4];
    const float* bk   = (const float*)d_in[5];
    const float* Wv   = (const float*)d_in[6];
    const float* bv   = (const float*)d_in[7];
    float* out = (float*)d_out;

    // workspace layout
    u16* xb = (u16*)d_ws;                              // bf16 [8192][1024]
    u16* Wb = xb + (size_t)MM * CC;                    // bf16 [3][1024][1024]
    u16* Qh = Wb + (size_t)3 * CC * CC;                // f16 [B,H,T,D]
    u16* Kh = Qh + (size_t)MM * CC;                    // f16 [B,H,T,D]
    u16* Vt = Kh + (size_t)MM * CC;                    // f16 [B,H,D,T], sigma key order
    float* fm = (float*)(Vt + (size_t)MM * CC);        // f32 [B,T] mask

    {
        int total = NX + 3 * NW + NM;
        cvt_all<<<(total + 255) / 256, 256, 0, stream>>>(x, Wq, Wk, Wv, mask, xb, Wb, fm);
    }

    qkv_gemm<<<dim3(CC / 128, MM / 128, 3), 256, 0, stream>>>(xb, Wb, bq, bk, bv, Qh, Kh, Vt);

    // grid: x=h (XCD affinity), y=q-tile, z=b
    attn_kernel<<<dim3(HH, TT / 256, BB), 256, 0, stream>>>(Qh, Kh, Vt, fm, out);
}